// Round 10
// baseline (255.798 us; speedup 1.0000x reference)
//
#include <hip/hip_runtime.h>

#define T_LEN 2048
#define DIM 2048
#define NH 16
#define HD 128
#define QKV_LD 6144   // 3*DIM

typedef __attribute__((ext_vector_type(8))) short short8;
typedef __attribute__((ext_vector_type(4))) short short4v;
typedef __attribute__((ext_vector_type(4))) float f32x4;
typedef __attribute__((ext_vector_type(4))) float float4v;
typedef __attribute__((ext_vector_type(4))) unsigned short ushort4v;
typedef __attribute__((ext_vector_type(2))) unsigned int uint2v;

static __device__ __forceinline__ unsigned short f2bf(float f) {
  unsigned u = __builtin_bit_cast(unsigned, f);
  u += 0x7fffu + ((u >> 16) & 1u);   // round-to-nearest-even
  return (unsigned short)(u >> 16);
}

static __device__ __forceinline__ float bf2f(unsigned short u) {
  unsigned x = ((unsigned)u) << 16;
  return __builtin_bit_cast(float, x);
}

static __device__ __forceinline__ float max3f(float a, float b, float c) {
  return fmaxf(fmaxf(a, b), c);      // clang fuses to v_max3_f32
}

static __device__ __forceinline__ f32x4 mfma16(short8 a, short8 b, f32x4 c) {
  return __builtin_amdgcn_mfma_f32_16x16x32_bf16(a, b, c, 0, 0, 0);
}

#define GLDS16(SRC, DST)                                                            \
  __builtin_amdgcn_global_load_lds((__attribute__((address_space(1))) void*)(SRC),  \
                                   (__attribute__((address_space(3))) void*)(DST),  \
                                   16, 0, 0)

// ---------------------------------------------------------------- fused casts
__global__ void cast3_f32_bf16(const float* __restrict__ a, unsigned short* __restrict__ oa, int na4,
                               const float* __restrict__ b, unsigned short* __restrict__ ob, int nb4,
                               const float* __restrict__ c, unsigned short* __restrict__ oc, int nc4) {
  const int stride = gridDim.x * blockDim.x;
  const int g = blockIdx.x * blockDim.x + threadIdx.x;
#define CAST_LOOP(SRC, DST, N4)                                  \
  for (int i = g; i < (N4); i += stride) {                       \
    float4v f = ((const float4v*)(SRC))[i];                      \
    ushort4v o;                                                  \
    o.x = f2bf(f.x); o.y = f2bf(f.y);                            \
    o.z = f2bf(f.z); o.w = f2bf(f.w);                            \
    ((ushort4v*)(DST))[i] = o;                                   \
  }
  CAST_LOOP(a, oa, na4)
  CAST_LOOP(b, ob, nb4)
  CAST_LOOP(c, oc, nc4)
#undef CAST_LOOP
}

// ---------------------------------------------------------------- GEMM 128x128 (m97)
// MODE 0: C f32 row-major. MODE 2: qkv fused — Q/K thirds bf16 row-major into
// Cv; V third transposed bf16 into vt[h][d][s].
template <int MODE>
__global__ __launch_bounds__(256) void gemm_bt_128(
    const unsigned short* __restrict__ A,
    const unsigned short* __restrict__ B,
    void* __restrict__ Cv, unsigned short* __restrict__ vt,
    int M, int N, int K) {
  __shared__ unsigned short As[128 * 64];
  __shared__ unsigned short Bs[128 * 64];
  const int tid = threadIdx.x;
  const int wave = tid >> 6;
  const int lane = tid & 63;
  const int l15 = lane & 15, l16 = lane >> 4;
  const int bm = blockIdx.y * 128;
  const int bn = blockIdx.x * 128;
  const int wr = wave >> 1, wc = wave & 1;

  f32x4 acc[4][4] = {};

  int srow[4], scol[4];
#pragma unroll
  for (int i = 0; i < 4; ++i) {
    int lin = i * 4096 + tid * 16;
    int row = lin >> 7;
    int cb = lin & 127;
    srow[i] = row;
    scol[i] = (cb ^ ((row & 7) << 4)) >> 1;
  }

  for (int k0 = 0; k0 < K; k0 += 64) {
#pragma unroll
    for (int i = 0; i < 4; ++i) {
      GLDS16(A + (size_t)(bm + srow[i]) * K + k0 + scol[i], As + i * 2048 + wave * 512);
      GLDS16(B + (size_t)(bn + srow[i]) * K + k0 + scol[i], Bs + i * 2048 + wave * 512);
    }
    __syncthreads();
#pragma unroll
    for (int kk = 0; kk < 2; ++kk) {
      const int cb = kk * 64 + l16 * 16;
      short8 af[4], bfr[4];
#pragma unroll
      for (int m = 0; m < 4; ++m) {
        int row = wr * 64 + m * 16 + l15;
        af[m] = *(const short8*)((const char*)As + row * 128 + (cb ^ ((row & 7) << 4)));
      }
#pragma unroll
      for (int n = 0; n < 4; ++n) {
        int row = wc * 64 + n * 16 + l15;
        bfr[n] = *(const short8*)((const char*)Bs + row * 128 + (cb ^ ((row & 7) << 4)));
      }
#pragma unroll
      for (int m = 0; m < 4; ++m)
#pragma unroll
        for (int n = 0; n < 4; ++n)
          acc[m][n] = mfma16(af[m], bfr[n], acc[m][n]);
    }
    __syncthreads();
  }

  const bool vthird = (MODE == 2) && (bn >= 2 * DIM);   // wave-uniform
#pragma unroll
  for (int m = 0; m < 4; ++m)
#pragma unroll
    for (int n = 0; n < 4; ++n) {
      int row = bm + wr * 64 + m * 16 + l16 * 4;
      int col = bn + wc * 64 + n * 16 + l15;
      if (MODE == 2 && vthird) {
        short4v w;
#pragma unroll
        for (int j = 0; j < 4; ++j) w[j] = (short)f2bf(acc[m][n][j]);
        *(short4v*)(vt + (size_t)(col - 2 * DIM) * T_LEN + row) = w;
      } else {
#pragma unroll
        for (int j = 0; j < 4; ++j) {
          if (MODE == 0)
            ((float*)Cv)[(size_t)(row + j) * N + col] = acc[m][n][j];
          else
            ((unsigned short*)Cv)[(size_t)(row + j) * N + col] = f2bf(acc[m][n][j]);
        }
      }
    }
}

// ---------------------------------------------------------------- flash attention, split-KV
// R3 core (4 waves x 16q, swapped QK^T, lane-local softmax, defer-max) with:
//  - V NOT LDS-staged: PV reads fragments directly from vt (L2-resident with
//    head-grouped XCD swizzle; m169 precedent) -> LDS 40KB (K dbuf + P only),
//    half the GLDS traffic and stage drain.
//  - split-KV x2 -> 1024 blocks; at 40KB LDS >=3 blocks/CU fit -> 3-4
//    waves/SIMD of latency hiding (vs 2). Partials merged by attn_combine.
__global__ __launch_bounds__(256) void attn_fwd(
    const unsigned short* __restrict__ qkv,
    const unsigned short* __restrict__ vt,
    unsigned short* __restrict__ po,    // [2][NH*T_LEN][HD] bf16 partial O
    float* __restrict__ ml) {           // [2][NH*T_LEN][2] f32 (m, l)
  __shared__ unsigned short Ks[2][64 * 128];
  __shared__ unsigned short Ps[4 * 16 * 64];
  const int tid = threadIdx.x;
  const int wave = tid >> 6;
  const int lane = tid & 63;
  const int l15 = lane & 15, l16 = lane >> 4;

  // XCD swizzle: 1024 wgs % 8 == 0 -> bijective; XCD x gets swz in
  // [x*128, x*128+128) = heads {2x, 2x+1} -> per-XCD K+V ~3MB < 4MB L2.
  const int wg = blockIdx.y * 64 + blockIdx.x;
  const int swz = (wg & 7) * 128 + (wg >> 3);
  const int h = swz >> 6;
  const int half = (swz >> 5) & 1;
  const int q0 = (swz & 31) * 64 + wave * 16;
  const int s_begin = half * (T_LEN / 2);
  const float SCL = 0.08838834764831845f * 1.4426950408889634f;  // 1/sqrt(128)*log2(e)

  short8 qf[4];
#pragma unroll
  for (int kk = 0; kk < 4; ++kk)
    qf[kk] = *(const short8*)(qkv + (size_t)(q0 + l15) * QKV_LD + h * HD + kk * 32 + l16 * 8);

  f32x4 acc_o[8] = {};
  float m_r = -1e30f;
  float l_r = 0.f;

  // K staging pointers (inverse-swizzled), bumped per tile
  const unsigned short* kp[4];
#pragma unroll
  for (int i = 0; i < 4; ++i) {
    int lin = i * 4096 + tid * 16;
    int r = lin >> 8;
    int cb = lin & 255;
    kp[i] = qkv + 2048 + h * HD + (size_t)(s_begin + r) * QKV_LD + ((cb ^ ((r & 7) << 4)) >> 1);
  }
  // V direct-read base: vt[h][d=l15-offset][s_begin + l16*8]
  const unsigned short* vrp = vt + (size_t)h * HD * T_LEN + (size_t)l15 * T_LEN +
                              s_begin + l16 * 8;

#define STAGE_K(BUF)                                                                   \
  do {                                                                                 \
    _Pragma("unroll")                                                                  \
    for (int i = 0; i < 4; ++i) {                                                      \
      GLDS16(kp[i], Ks[BUF] + i * 2048 + wave * 512);                                  \
      kp[i] += 64 * QKV_LD;                                                            \
    }                                                                                  \
  } while (0)

  STAGE_K(0);
  __syncthreads();

  const int NT = (T_LEN / 2) / 64;   // 16 tiles per half
  int cur = 0;
  for (int t = 0; t < NT; ++t) {
    if (t + 1 < NT) STAGE_K(cur ^ 1);

    const unsigned short* ks = Ks[cur];

    // S^T = K Q^T : lane (l15,l16) holds S[kv = c*16 + l16*4 + j][q = l15]
    f32x4 st[4] = {};
#pragma unroll
    for (int c = 0; c < 4; ++c) {
#pragma unroll
      for (int kk = 0; kk < 4; ++kk) {
        int row = c * 16 + l15;
        int cb = kk * 64 + l16 * 16;
        short8 kf = *(const short8*)((const char*)ks + row * 256 + (cb ^ ((row & 7) << 4)));
        st[c] = mfma16(kf, qf[kk], st[c]);
      }
    }

    // online softmax, lane-local for q-row l15
    float ma = max3f(st[0][0], st[0][1], st[0][2]);
    float mb = max3f(st[0][3], st[1][0], st[1][1]);
    float mc = max3f(st[1][2], st[1][3], st[2][0]);
    float md = max3f(st[2][1], st[2][2], st[2][3]);
    float me = max3f(st[3][0], st[3][1], st[3][2]);
    float pmax = fmaxf(max3f(ma, mb, mc), max3f(md, me, st[3][3])) * SCL;
    pmax = fmaxf(pmax, __shfl_xor(pmax, 16));
    pmax = fmaxf(pmax, __shfl_xor(pmax, 32));

    if (!__all(pmax - m_r <= 8.0f)) {
      float nm = fmaxf(m_r, pmax);
      float corr = __builtin_amdgcn_exp2f(m_r - nm);
      m_r = nm;
      l_r *= corr;
      float cj[4];
#pragma unroll
      for (int j = 0; j < 4; ++j) cj[j] = __shfl(corr, l16 * 4 + j);
#pragma unroll
      for (int d = 0; d < 8; ++d)
#pragma unroll
        for (int j = 0; j < 4; ++j) acc_o[d][j] *= cj[j];
    }

    float p[4][4];
#pragma unroll
    for (int c = 0; c < 4; ++c)
#pragma unroll
      for (int j = 0; j < 4; ++j)
        p[c][j] = __builtin_amdgcn_exp2f(st[c][j] * SCL - m_r);
    float s01 = (p[0][0] + p[0][1]) + (p[0][2] + p[0][3]);
    float s23 = (p[1][0] + p[1][1]) + (p[1][2] + p[1][3]);
    float s45 = (p[2][0] + p[2][1]) + (p[2][2] + p[2][3]);
    float s67 = (p[3][0] + p[3][1]) + (p[3][2] + p[3][3]);
    float tsum = (s01 + s23) + (s45 + s67);
    tsum += __shfl_xor(tsum, 16);
    tsum += __shfl_xor(tsum, 32);
    l_r += tsum;

    char* pbase = (char*)Ps + wave * 2048;
#pragma unroll
    for (int c = 0; c < 4; ++c) {
      uint2v w;
      w.x = (unsigned)f2bf(p[c][0]) | ((unsigned)f2bf(p[c][1]) << 16);
      w.y = (unsigned)f2bf(p[c][2]) | ((unsigned)f2bf(p[c][3]) << 16);
      int off = l15 * 128 + c * 32 + l16 * 8;
      *(uint2v*)(pbase + (off ^ ((l15 & 7) << 4))) = w;
    }

    // ctx += P @ V ; V fragments read DIRECTLY from vt (L2)
    const unsigned short* vtile = vrp + t * 64;
#pragma unroll
    for (int kk = 0; kk < 2; ++kk) {
      int cb = kk * 64 + l16 * 16;
      short8 pa = *(const short8*)(pbase + l15 * 128 + (cb ^ ((l15 & 7) << 4)));
#pragma unroll
      for (int d = 0; d < 8; ++d) {
        short8 vb = *(const short8*)(vtile + (size_t)d * 16 * T_LEN + kk * 32);
        acc_o[d] = mfma16(pa, vb, acc_o[d]);
      }
    }

    __syncthreads();   // Ks[cur^1] staged; Ps safe (per-wave) — barrier for K reuse
    cur ^= 1;
  }
#undef STAGE_K

  // epilogue: write UNNORMALIZED partials
  const size_t pb = ((size_t)half * NH * T_LEN + (size_t)h * T_LEN) * HD;
#pragma unroll
  for (int d = 0; d < 8; ++d)
#pragma unroll
    for (int j = 0; j < 4; ++j) {
      int q = q0 + l16 * 4 + j;
      po[pb + (size_t)q * HD + d * 16 + l15] = f2bf(acc_o[d][j]);
    }
  if (l16 == 0) {
    size_t mlbase = ((size_t)half * NH * T_LEN + (size_t)h * T_LEN + q0 + l15) * 2;
    ml[mlbase] = m_r;
    ml[mlbase + 1] = l_r;
  }
}

// ---------------------------------------------------------------- combine halves
__global__ __launch_bounds__(256) void attn_combine(
    const unsigned short* __restrict__ po, const float* __restrict__ ml,
    unsigned short* __restrict__ ctx) {
  const int g = blockIdx.x * 256 + threadIdx.x;   // 524288 total
  const int hq = g >> 4;          // h*T_LEN + q
  const int oct = g & 15;         // d-octet
  const float m0 = ml[hq * 2], l0 = ml[hq * 2 + 1];
  const float m1 = ml[NH * T_LEN * 2 + hq * 2], l1 = ml[NH * T_LEN * 2 + hq * 2 + 1];
  const float m = fmaxf(m0, m1);
  float a0 = __builtin_amdgcn_exp2f(m0 - m);
  float a1 = __builtin_amdgcn_exp2f(m1 - m);
  const float rl = 1.0f / (l0 * a0 + l1 * a1);
  a0 *= rl; a1 *= rl;
  const short8 o0 = *(const short8*)(po + (size_t)hq * HD + oct * 8);
  const short8 o1 = *(const short8*)(po + (size_t)NH * T_LEN * HD + (size_t)hq * HD + oct * 8);
  short8 w;
#pragma unroll
  for (int j = 0; j < 8; ++j)
    w[j] = (short)f2bf(bf2f((unsigned short)o0[j]) * a0 + bf2f((unsigned short)o1[j]) * a1);
  const int h = hq >> 11, q = hq & (T_LEN - 1);
  *(short8*)(ctx + (size_t)q * DIM + h * HD + oct * 8) = w;
}

// ---------------------------------------------------------------- launcher
extern "C" void kernel_launch(void* const* d_in, const int* in_sizes, int n_in,
                              void* d_out, int out_size, void* d_ws, size_t ws_size,
                              hipStream_t stream) {
  const float* x = (const float*)d_in[0];
  const float* w_in = (const float*)d_in[1];
  const float* w_out = (const float*)d_in[2];

  char* ws = (char*)d_ws;
  unsigned short* xbf  = (unsigned short*)(ws + 0);          //  8 MB
  unsigned short* wibf = (unsigned short*)(ws + 8388608);    // 24 MB
  unsigned short* wobf = (unsigned short*)(ws + 33554432);   //  8 MB
  unsigned short* qkv  = (unsigned short*)(ws + 41943040);   // 24 MB (V third unused)
  unsigned short* ctx  = (unsigned short*)(ws + 67108864);   //  8 MB
  unsigned short* vt   = (unsigned short*)(ws + 75497472);   //  8 MB  (end: 80 MB)
  // attention partials REUSE xbf+wibf region [0, 32MB) — dead after GEMM1:
  unsigned short* po   = (unsigned short*)(ws + 0);          // 16 MB
  float*          ml   = (float*)(ws + 16777216);            // 512 KB

  // fused fp32->bf16 casts (x, w_in, w_out) in one launch
  cast3_f32_bf16<<<2048, 256, 0, stream>>>(
      x, xbf, (T_LEN * DIM) / 4,
      w_in, wibf, (3 * DIM * DIM) / 4,
      w_out, wobf, (DIM * DIM) / 4);

  // qkv = x @ w_in^T; V third written TRANSPOSED directly into vt
  gemm_bt_128<2><<<dim3(48, 16), 256, 0, stream>>>(
      xbf, wibf, (void*)qkv, vt, T_LEN, 3 * DIM, DIM);
  // attention partials (split-KV, V direct from L2), then combine -> ctx
  attn_fwd<<<dim3(64, 16), 256, 0, stream>>>(qkv, vt, po, ml);
  attn_combine<<<2048, 256, 0, stream>>>(po, ml, ctx);
  // out = ctx @ w_out^T  (fp32)
  gemm_bt_128<0><<<dim3(16, 16), 256, 0, stream>>>(
      ctx, wobf, d_out, nullptr, T_LEN, DIM, DIM);
}

// Round 11
// 175.543 us; speedup vs baseline: 1.4572x; 1.4572x over previous
//
#include <hip/hip_runtime.h>

#define T_LEN 2048
#define DIM 2048
#define NH 16
#define HD 128
#define QKV_LD 6144   // 3*DIM

typedef __attribute__((ext_vector_type(8))) short short8;
typedef __attribute__((ext_vector_type(4))) short short4v;
typedef __attribute__((ext_vector_type(4))) float f32x4;
typedef __attribute__((ext_vector_type(4))) float float4v;
typedef __attribute__((ext_vector_type(4))) unsigned short ushort4v;
typedef __attribute__((ext_vector_type(2))) unsigned int uint2v;

static __device__ __forceinline__ unsigned short f2bf(float f) {
  unsigned u = __builtin_bit_cast(unsigned, f);
  u += 0x7fffu + ((u >> 16) & 1u);   // round-to-nearest-even
  return (unsigned short)(u >> 16);
}

static __device__ __forceinline__ float max3f(float a, float b, float c) {
  return fmaxf(fmaxf(a, b), c);      // clang fuses to v_max3_f32
}

static __device__ __forceinline__ f32x4 mfma16(short8 a, short8 b, f32x4 c) {
  return __builtin_amdgcn_mfma_f32_16x16x32_bf16(a, b, c, 0, 0, 0);
}

#define GLDS16(SRC, DST)                                                            \
  __builtin_amdgcn_global_load_lds((__attribute__((address_space(1))) void*)(SRC),  \
                                   (__attribute__((address_space(3))) void*)(DST),  \
                                   16, 0, 0)

// ---------------------------------------------------------------- fused casts
__global__ void cast3_f32_bf16(const float* __restrict__ a, unsigned short* __restrict__ oa, int na4,
                               const float* __restrict__ b, unsigned short* __restrict__ ob, int nb4,
                               const float* __restrict__ c, unsigned short* __restrict__ oc, int nc4) {
  const int stride = gridDim.x * blockDim.x;
  const int g = blockIdx.x * blockDim.x + threadIdx.x;
#define CAST_LOOP(SRC, DST, N4)                                  \
  for (int i = g; i < (N4); i += stride) {                       \
    float4v f = ((const float4v*)(SRC))[i];                      \
    ushort4v o;                                                  \
    o.x = f2bf(f.x); o.y = f2bf(f.y);                            \
    o.z = f2bf(f.z); o.w = f2bf(f.w);                            \
    ((ushort4v*)(DST))[i] = o;                                   \
  }
  CAST_LOOP(a, oa, na4)
  CAST_LOOP(b, ob, nb4)
  CAST_LOOP(c, oc, nc4)
#undef CAST_LOOP
}

// ---------------------------------------------------------------- GEMM 128x128 (m97)
// MODE 2: qkv fused — Q/K thirds bf16 row-major into Cv; V third transposed
// bf16 into vt[h][d][s].
template <int MODE>
__global__ __launch_bounds__(256) void gemm_bt_128(
    const unsigned short* __restrict__ A,
    const unsigned short* __restrict__ B,
    void* __restrict__ Cv, unsigned short* __restrict__ vt,
    int M, int N, int K) {
  __shared__ unsigned short As[128 * 64];
  __shared__ unsigned short Bs[128 * 64];
  const int tid = threadIdx.x;
  const int wave = tid >> 6;
  const int lane = tid & 63;
  const int l15 = lane & 15, l16 = lane >> 4;
  const int bm = blockIdx.y * 128;
  const int bn = blockIdx.x * 128;
  const int wr = wave >> 1, wc = wave & 1;

  f32x4 acc[4][4] = {};

  int srow[4], scol[4];
#pragma unroll
  for (int i = 0; i < 4; ++i) {
    int lin = i * 4096 + tid * 16;
    int row = lin >> 7;
    int cb = lin & 127;
    srow[i] = row;
    scol[i] = (cb ^ ((row & 7) << 4)) >> 1;
  }

  for (int k0 = 0; k0 < K; k0 += 64) {
#pragma unroll
    for (int i = 0; i < 4; ++i) {
      GLDS16(A + (size_t)(bm + srow[i]) * K + k0 + scol[i], As + i * 2048 + wave * 512);
      GLDS16(B + (size_t)(bn + srow[i]) * K + k0 + scol[i], Bs + i * 2048 + wave * 512);
    }
    __syncthreads();
#pragma unroll
    for (int kk = 0; kk < 2; ++kk) {
      const int cb = kk * 64 + l16 * 16;
      short8 af[4], bfr[4];
#pragma unroll
      for (int m = 0; m < 4; ++m) {
        int row = wr * 64 + m * 16 + l15;
        af[m] = *(const short8*)((const char*)As + row * 128 + (cb ^ ((row & 7) << 4)));
      }
#pragma unroll
      for (int n = 0; n < 4; ++n) {
        int row = wc * 64 + n * 16 + l15;
        bfr[n] = *(const short8*)((const char*)Bs + row * 128 + (cb ^ ((row & 7) << 4)));
      }
#pragma unroll
      for (int m = 0; m < 4; ++m)
#pragma unroll
        for (int n = 0; n < 4; ++n)
          acc[m][n] = mfma16(af[m], bfr[n], acc[m][n]);
    }
    __syncthreads();
  }

  const bool vthird = (MODE == 2) && (bn >= 2 * DIM);   // wave-uniform
#pragma unroll
  for (int m = 0; m < 4; ++m)
#pragma unroll
    for (int n = 0; n < 4; ++n) {
      int row = bm + wr * 64 + m * 16 + l16 * 4;
      int col = bn + wc * 64 + n * 16 + l15;
      if (MODE == 2 && vthird) {
        short4v w;
#pragma unroll
        for (int j = 0; j < 4; ++j) w[j] = (short)f2bf(acc[m][n][j]);
        *(short4v*)(vt + (size_t)(col - 2 * DIM) * T_LEN + row) = w;
      } else {
#pragma unroll
        for (int j = 0; j < 4; ++j) {
          if (MODE == 0)
            ((float*)Cv)[(size_t)(row + j) * N + col] = acc[m][n][j];
          else
            ((unsigned short*)Cv)[(size_t)(row + j) * N + col] = f2bf(acc[m][n][j]);
        }
      }
    }
}

// ---------------------------------------------------------------- GEMM 128x64 (f32 out)
// Same m97 structure, half-width N tile -> 512 blocks for 2048x2048 = 2
// blocks/CU: the second resident block absorbs the per-K-step barrier drain
// that is fully exposed at 1 block/CU (R10 ledger: GEMM2 = 26us at grid 256).
__global__ __launch_bounds__(256) void gemm_bt_12864(
    const unsigned short* __restrict__ A,
    const unsigned short* __restrict__ B,
    float* __restrict__ C, int M, int N, int K) {
  __shared__ unsigned short As[128 * 64];
  __shared__ unsigned short Bs[64 * 64];
  const int tid = threadIdx.x;
  const int wave = tid >> 6;
  const int lane = tid & 63;
  const int l15 = lane & 15, l16 = lane >> 4;
  const int bm = blockIdx.y * 128;
  const int bn = blockIdx.x * 64;
  const int wr = wave >> 1, wc = wave & 1;

  f32x4 acc[4][2] = {};

  int srow[4], scol[4];
#pragma unroll
  for (int i = 0; i < 4; ++i) {
    int lin = i * 4096 + tid * 16;
    int row = lin >> 7;
    int cb = lin & 127;
    srow[i] = row;
    scol[i] = (cb ^ ((row & 7) << 4)) >> 1;
  }

  for (int k0 = 0; k0 < K; k0 += 64) {
#pragma unroll
    for (int i = 0; i < 4; ++i)
      GLDS16(A + (size_t)(bm + srow[i]) * K + k0 + scol[i], As + i * 2048 + wave * 512);
#pragma unroll
    for (int i = 0; i < 2; ++i)
      GLDS16(B + (size_t)(bn + srow[i]) * K + k0 + scol[i], Bs + i * 2048 + wave * 512);
    __syncthreads();
#pragma unroll
    for (int kk = 0; kk < 2; ++kk) {
      const int cb = kk * 64 + l16 * 16;
      short8 af[4], bfr[2];
#pragma unroll
      for (int m = 0; m < 4; ++m) {
        int row = wr * 64 + m * 16 + l15;
        af[m] = *(const short8*)((const char*)As + row * 128 + (cb ^ ((row & 7) << 4)));
      }
#pragma unroll
      for (int n = 0; n < 2; ++n) {
        int row = wc * 32 + n * 16 + l15;
        bfr[n] = *(const short8*)((const char*)Bs + row * 128 + (cb ^ ((row & 7) << 4)));
      }
#pragma unroll
      for (int m = 0; m < 4; ++m)
#pragma unroll
        for (int n = 0; n < 2; ++n)
          acc[m][n] = mfma16(af[m], bfr[n], acc[m][n]);
    }
    __syncthreads();
  }

#pragma unroll
  for (int m = 0; m < 4; ++m)
#pragma unroll
    for (int n = 0; n < 2; ++n) {
      int row = bm + wr * 64 + m * 16 + l16 * 4;
      int col = bn + wc * 32 + n * 16 + l15;
#pragma unroll
      for (int j = 0; j < 4; ++j)
        C[(size_t)(row + j) * N + col] = acc[m][n][j];
    }
}

// ---------------------------------------------------------------- flash attention
// R3-EXACT (measured 81.5us): 4 waves x 16q, KV tile 64, K+V double-buffered
// via global_load_lds, prefetch-before-compute, one barrier/iter, swapped
// QK^T, lane-local softmax, defer-max. No XCD swizzle (+2us, R9 isolation),
// no setprio (+2us, R8/R9 isolation), no split-KV (R5/R10: occupancy pinned).
__global__ __launch_bounds__(256) void attn_fwd(
    const unsigned short* __restrict__ qkv,
    const unsigned short* __restrict__ vt,
    unsigned short* __restrict__ ctx) {
  __shared__ unsigned short Ks[2][64 * 128];
  __shared__ unsigned short Vs[2][128 * 64];
  __shared__ unsigned short Ps[4 * 16 * 64];
  const int tid = threadIdx.x;
  const int wave = tid >> 6;
  const int lane = tid & 63;
  const int l15 = lane & 15, l16 = lane >> 4;
  const int h = blockIdx.y;
  const int q0 = blockIdx.x * 64 + wave * 16;
  const float SCL = 0.08838834764831845f * 1.4426950408889634f;  // 1/sqrt(128)*log2(e)

  short8 qf[4];
#pragma unroll
  for (int kk = 0; kk < 4; ++kk)
    qf[kk] = *(const short8*)(qkv + (size_t)(q0 + l15) * QKV_LD + h * HD + kk * 32 + l16 * 8);

  f32x4 acc_o[8] = {};
  float m_r = -1e30f;
  float l_r = 0.f;

  int krow[4], kcol[4], vrow[4], vcol[4];
#pragma unroll
  for (int i = 0; i < 4; ++i) {
    int lin = i * 4096 + tid * 16;
    int r = lin >> 8;
    int cb = lin & 255;
    krow[i] = r; kcol[i] = (cb ^ ((r & 7) << 4)) >> 1;
    r = lin >> 7;
    cb = lin & 127;
    vrow[i] = r; vcol[i] = (cb ^ ((r & 7) << 4)) >> 1;
  }
  const unsigned short* kbase = qkv + 2048 + h * HD;
  const unsigned short* vbase = vt + (size_t)h * HD * T_LEN;

#define STAGE_KV(BUF, S0)                                                              \
  do {                                                                                 \
    _Pragma("unroll")                                                                  \
    for (int i = 0; i < 4; ++i) {                                                      \
      GLDS16(kbase + (size_t)((S0) + krow[i]) * QKV_LD + kcol[i],                      \
             Ks[BUF] + i * 2048 + wave * 512);                                         \
      GLDS16(vbase + (size_t)vrow[i] * T_LEN + (S0) + vcol[i],                         \
             Vs[BUF] + i * 2048 + wave * 512);                                         \
    }                                                                                  \
  } while (0)

  STAGE_KV(0, 0);
  __syncthreads();

  const int NT = T_LEN / 64;
  int cur = 0;
  for (int t = 0; t < NT; ++t) {
    if (t + 1 < NT) STAGE_KV(cur ^ 1, (t + 1) * 64);

    const unsigned short* ks = Ks[cur];
    const unsigned short* vs = Vs[cur];

    // S^T = K Q^T : lane (l15,l16) holds S[kv = c*16 + l16*4 + j][q = l15]
    f32x4 st[4] = {};
#pragma unroll
    for (int c = 0; c < 4; ++c) {
#pragma unroll
      for (int kk = 0; kk < 4; ++kk) {
        int row = c * 16 + l15;
        int cb = kk * 64 + l16 * 16;
        short8 kf = *(const short8*)((const char*)ks + row * 256 + (cb ^ ((row & 7) << 4)));
        st[c] = mfma16(kf, qf[kk], st[c]);
      }
    }

    // online softmax, lane-local for q-row l15
    float ma = max3f(st[0][0], st[0][1], st[0][2]);
    float mb = max3f(st[0][3], st[1][0], st[1][1]);
    float mc = max3f(st[1][2], st[1][3], st[2][0]);
    float md = max3f(st[2][1], st[2][2], st[2][3]);
    float me = max3f(st[3][0], st[3][1], st[3][2]);
    float pmax = fmaxf(max3f(ma, mb, mc), max3f(md, me, st[3][3])) * SCL;
    pmax = fmaxf(pmax, __shfl_xor(pmax, 16));
    pmax = fmaxf(pmax, __shfl_xor(pmax, 32));

    if (!__all(pmax - m_r <= 8.0f)) {
      float nm = fmaxf(m_r, pmax);
      float corr = __builtin_amdgcn_exp2f(m_r - nm);
      m_r = nm;
      l_r *= corr;
      float cj[4];
#pragma unroll
      for (int j = 0; j < 4; ++j) cj[j] = __shfl(corr, l16 * 4 + j);
#pragma unroll
      for (int d = 0; d < 8; ++d)
#pragma unroll
        for (int j = 0; j < 4; ++j) acc_o[d][j] *= cj[j];
    }

    float p[4][4];
#pragma unroll
    for (int c = 0; c < 4; ++c)
#pragma unroll
      for (int j = 0; j < 4; ++j)
        p[c][j] = __builtin_amdgcn_exp2f(st[c][j] * SCL - m_r);
    float s01 = (p[0][0] + p[0][1]) + (p[0][2] + p[0][3]);
    float s23 = (p[1][0] + p[1][1]) + (p[1][2] + p[1][3]);
    float s45 = (p[2][0] + p[2][1]) + (p[2][2] + p[2][3]);
    float s67 = (p[3][0] + p[3][1]) + (p[3][2] + p[3][3]);
    float tsum = (s01 + s23) + (s45 + s67);
    tsum += __shfl_xor(tsum, 16);
    tsum += __shfl_xor(tsum, 32);
    l_r += tsum;

    char* pbase = (char*)Ps + wave * 2048;
#pragma unroll
    for (int c = 0; c < 4; ++c) {
      uint2v w;
      w.x = (unsigned)f2bf(p[c][0]) | ((unsigned)f2bf(p[c][1]) << 16);
      w.y = (unsigned)f2bf(p[c][2]) | ((unsigned)f2bf(p[c][3]) << 16);
      int off = l15 * 128 + c * 32 + l16 * 8;
      *(uint2v*)(pbase + (off ^ ((l15 & 7) << 4))) = w;
    }

#pragma unroll
    for (int kk = 0; kk < 2; ++kk) {
      int cb = kk * 64 + l16 * 16;
      short8 pa = *(const short8*)(pbase + l15 * 128 + (cb ^ ((l15 & 7) << 4)));
#pragma unroll
      for (int d = 0; d < 8; ++d) {
        int row = d * 16 + l15;
        short8 vb = *(const short8*)((const char*)vs + row * 128 + (cb ^ ((row & 7) << 4)));
        acc_o[d] = mfma16(pa, vb, acc_o[d]);
      }
    }

    __syncthreads();
    cur ^= 1;
  }
#undef STAGE_KV

  float lq[4];
#pragma unroll
  for (int j = 0; j < 4; ++j) lq[j] = 1.0f / __shfl(l_r, l16 * 4 + j);
#pragma unroll
  for (int d = 0; d < 8; ++d)
#pragma unroll
    for (int j = 0; j < 4; ++j) {
      int row = q0 + l16 * 4 + j;
      int col = h * HD + d * 16 + l15;
      ctx[(size_t)row * DIM + col] = f2bf(acc_o[d][j] * lq[j]);
    }
}

// ---------------------------------------------------------------- launcher
extern "C" void kernel_launch(void* const* d_in, const int* in_sizes, int n_in,
                              void* d_out, int out_size, void* d_ws, size_t ws_size,
                              hipStream_t stream) {
  const float* x = (const float*)d_in[0];
  const float* w_in = (const float*)d_in[1];
  const float* w_out = (const float*)d_in[2];

  char* ws = (char*)d_ws;
  unsigned short* xbf  = (unsigned short*)(ws + 0);          //  8 MB
  unsigned short* wibf = (unsigned short*)(ws + 8388608);    // 24 MB
  unsigned short* wobf = (unsigned short*)(ws + 33554432);   //  8 MB
  unsigned short* qkv  = (unsigned short*)(ws + 41943040);   // 24 MB (V third unused)
  unsigned short* ctx  = (unsigned short*)(ws + 67108864);   //  8 MB
  unsigned short* vt   = (unsigned short*)(ws + 75497472);   //  8 MB  (end: 80 MB)

  // fused fp32->bf16 casts (x, w_in, w_out) in one launch
  cast3_f32_bf16<<<2048, 256, 0, stream>>>(
      x, xbf, (T_LEN * DIM) / 4,
      w_in, wibf, (3 * DIM * DIM) / 4,
      w_out, wobf, (DIM * DIM) / 4);

  // qkv = x @ w_in^T; V third written TRANSPOSED directly into vt
  gemm_bt_128<2><<<dim3(48, 16), 256, 0, stream>>>(
      xbf, wibf, (void*)qkv, vt, T_LEN, 3 * DIM, DIM);
  // attention -> ctx [2048 x 2048] bf16
  attn_fwd<<<dim3(32, 16), 256, 0, stream>>>(qkv, vt, ctx);
  // out = ctx @ w_out^T  (fp32) — 128x64 tiles, 512 blocks = 2/CU
  gemm_bt_12864<<<dim3(32, 16), 256, 0, stream>>>(ctx, wobf, (float*)d_out, T_LEN, DIM, DIM);
}

// Round 12
// 169.724 us; speedup vs baseline: 1.5071x; 1.0343x over previous
//
#include <hip/hip_runtime.h>

#define T_LEN 2048
#define DIM 2048
#define NH 16
#define HD 128
#define QKV_LD 6144   // 3*DIM

typedef __attribute__((ext_vector_type(8))) short short8;
typedef __attribute__((ext_vector_type(4))) short short4v;
typedef __attribute__((ext_vector_type(4))) float f32x4;
typedef __attribute__((ext_vector_type(4))) float float4v;
typedef __attribute__((ext_vector_type(4))) unsigned short ushort4v;
typedef __attribute__((ext_vector_type(2))) unsigned int uint2v;

static __device__ __forceinline__ unsigned short f2bf(float f) {
  unsigned u = __builtin_bit_cast(unsigned, f);
  u += 0x7fffu + ((u >> 16) & 1u);   // round-to-nearest-even
  return (unsigned short)(u >> 16);
}

static __device__ __forceinline__ unsigned cvtpk_bf16(float lo, float hi) {
  unsigned r;
  asm("v_cvt_pk_bf16_f32 %0, %1, %2" : "=v"(r) : "v"(lo), "v"(hi));
  return r;   // lo in bits [15:0], hi in [31:16], RNE
}

static __device__ __forceinline__ float max3f(float a, float b, float c) {
  return fmaxf(fmaxf(a, b), c);      // clang fuses to v_max3_f32
}

static __device__ __forceinline__ f32x4 mfma16(short8 a, short8 b, f32x4 c) {
  return __builtin_amdgcn_mfma_f32_16x16x32_bf16(a, b, c, 0, 0, 0);
}

#define GLDS16(SRC, DST)                                                            \
  __builtin_amdgcn_global_load_lds((__attribute__((address_space(1))) void*)(SRC),  \
                                   (__attribute__((address_space(3))) void*)(DST),  \
                                   16, 0, 0)

// ---------------------------------------------------------------- fused casts
__global__ void cast3_f32_bf16(const float* __restrict__ a, unsigned short* __restrict__ oa, int na4,
                               const float* __restrict__ b, unsigned short* __restrict__ ob, int nb4,
                               const float* __restrict__ c, unsigned short* __restrict__ oc, int nc4) {
  const int stride = gridDim.x * blockDim.x;
  const int g = blockIdx.x * blockDim.x + threadIdx.x;
#define CAST_LOOP(SRC, DST, N4)                                  \
  for (int i = g; i < (N4); i += stride) {                       \
    float4v f = ((const float4v*)(SRC))[i];                      \
    ushort4v o;                                                  \
    o.x = f2bf(f.x); o.y = f2bf(f.y);                            \
    o.z = f2bf(f.z); o.w = f2bf(f.w);                            \
    ((ushort4v*)(DST))[i] = o;                                   \
  }
  CAST_LOOP(a, oa, na4)
  CAST_LOOP(b, ob, nb4)
  CAST_LOOP(c, oc, nc4)
#undef CAST_LOOP
}

// ---------------------------------------------------------------- GEMM 128x128 (m97)
// MODE 2: qkv fused — Q/K thirds bf16 row-major into Cv; V third transposed
// bf16 into vt[h][d][s].
template <int MODE>
__global__ __launch_bounds__(256) void gemm_bt_128(
    const unsigned short* __restrict__ A,
    const unsigned short* __restrict__ B,
    void* __restrict__ Cv, unsigned short* __restrict__ vt,
    int M, int N, int K) {
  __shared__ unsigned short As[128 * 64];
  __shared__ unsigned short Bs[128 * 64];
  const int tid = threadIdx.x;
  const int wave = tid >> 6;
  const int lane = tid & 63;
  const int l15 = lane & 15, l16 = lane >> 4;
  const int bm = blockIdx.y * 128;
  const int bn = blockIdx.x * 128;
  const int wr = wave >> 1, wc = wave & 1;

  f32x4 acc[4][4] = {};

  int srow[4], scol[4];
#pragma unroll
  for (int i = 0; i < 4; ++i) {
    int lin = i * 4096 + tid * 16;
    int row = lin >> 7;
    int cb = lin & 127;
    srow[i] = row;
    scol[i] = (cb ^ ((row & 7) << 4)) >> 1;
  }

  for (int k0 = 0; k0 < K; k0 += 64) {
#pragma unroll
    for (int i = 0; i < 4; ++i) {
      GLDS16(A + (size_t)(bm + srow[i]) * K + k0 + scol[i], As + i * 2048 + wave * 512);
      GLDS16(B + (size_t)(bn + srow[i]) * K + k0 + scol[i], Bs + i * 2048 + wave * 512);
    }
    __syncthreads();
#pragma unroll
    for (int kk = 0; kk < 2; ++kk) {
      const int cb = kk * 64 + l16 * 16;
      short8 af[4], bfr[4];
#pragma unroll
      for (int m = 0; m < 4; ++m) {
        int row = wr * 64 + m * 16 + l15;
        af[m] = *(const short8*)((const char*)As + row * 128 + (cb ^ ((row & 7) << 4)));
      }
#pragma unroll
      for (int n = 0; n < 4; ++n) {
        int row = wc * 64 + n * 16 + l15;
        bfr[n] = *(const short8*)((const char*)Bs + row * 128 + (cb ^ ((row & 7) << 4)));
      }
#pragma unroll
      for (int m = 0; m < 4; ++m)
#pragma unroll
        for (int n = 0; n < 4; ++n)
          acc[m][n] = mfma16(af[m], bfr[n], acc[m][n]);
    }
    __syncthreads();
  }

  const bool vthird = (MODE == 2) && (bn >= 2 * DIM);   // wave-uniform
#pragma unroll
  for (int m = 0; m < 4; ++m)
#pragma unroll
    for (int n = 0; n < 4; ++n) {
      int row = bm + wr * 64 + m * 16 + l16 * 4;
      int col = bn + wc * 64 + n * 16 + l15;
      if (MODE == 2 && vthird) {
        short4v w;
#pragma unroll
        for (int j = 0; j < 4; ++j) w[j] = (short)f2bf(acc[m][n][j]);
        *(short4v*)(vt + (size_t)(col - 2 * DIM) * T_LEN + row) = w;
      } else {
#pragma unroll
        for (int j = 0; j < 4; ++j) {
          if (MODE == 0)
            ((float*)Cv)[(size_t)(row + j) * N + col] = acc[m][n][j];
          else
            ((unsigned short*)Cv)[(size_t)(row + j) * N + col] = f2bf(acc[m][n][j]);
        }
      }
    }
}

// ---------------------------------------------------------------- GEMM 128x64 (f32 out)
__global__ __launch_bounds__(256) void gemm_bt_12864(
    const unsigned short* __restrict__ A,
    const unsigned short* __restrict__ B,
    float* __restrict__ C, int M, int N, int K) {
  __shared__ unsigned short As[128 * 64];
  __shared__ unsigned short Bs[64 * 64];
  const int tid = threadIdx.x;
  const int wave = tid >> 6;
  const int lane = tid & 63;
  const int l15 = lane & 15, l16 = lane >> 4;
  const int bm = blockIdx.y * 128;
  const int bn = blockIdx.x * 64;
  const int wr = wave >> 1, wc = wave & 1;

  f32x4 acc[4][2] = {};

  int srow[4], scol[4];
#pragma unroll
  for (int i = 0; i < 4; ++i) {
    int lin = i * 4096 + tid * 16;
    int row = lin >> 7;
    int cb = lin & 127;
    srow[i] = row;
    scol[i] = (cb ^ ((row & 7) << 4)) >> 1;
  }

  for (int k0 = 0; k0 < K; k0 += 64) {
#pragma unroll
    for (int i = 0; i < 4; ++i)
      GLDS16(A + (size_t)(bm + srow[i]) * K + k0 + scol[i], As + i * 2048 + wave * 512);
#pragma unroll
    for (int i = 0; i < 2; ++i)
      GLDS16(B + (size_t)(bn + srow[i]) * K + k0 + scol[i], Bs + i * 2048 + wave * 512);
    __syncthreads();
#pragma unroll
    for (int kk = 0; kk < 2; ++kk) {
      const int cb = kk * 64 + l16 * 16;
      short8 af[4], bfr[2];
#pragma unroll
      for (int m = 0; m < 4; ++m) {
        int row = wr * 64 + m * 16 + l15;
        af[m] = *(const short8*)((const char*)As + row * 128 + (cb ^ ((row & 7) << 4)));
      }
#pragma unroll
      for (int n = 0; n < 2; ++n) {
        int row = wc * 32 + n * 16 + l15;
        bfr[n] = *(const short8*)((const char*)Bs + row * 128 + (cb ^ ((row & 7) << 4)));
      }
#pragma unroll
      for (int m = 0; m < 4; ++m)
#pragma unroll
        for (int n = 0; n < 2; ++n)
          acc[m][n] = mfma16(af[m], bfr[n], acc[m][n]);
    }
    __syncthreads();
  }

#pragma unroll
  for (int m = 0; m < 4; ++m)
#pragma unroll
    for (int n = 0; n < 2; ++n) {
      int row = bm + wr * 64 + m * 16 + l16 * 4;
      int col = bn + wc * 32 + n * 16 + l15;
#pragma unroll
      for (int j = 0; j < 4; ++j)
        C[(size_t)(row + j) * N + col] = acc[m][n][j];
    }
}

// ---------------------------------------------------------------- flash attention
// R3 structure (4 waves x 16q, KV tile 64, dbuf, prefetch-before-compute, one
// barrier/iter, swapped QK^T, lane-local softmax, defer-max) with VALU diet:
//  - all LDS accesses via 8 loop-invariant per-lane base pointers + ds offset
//    immediates (exploits (row&7)==(l15&7) for every tile read);
//  - t-loop unrolled x2 so the dbuf offset (+16384B) is compile-time;
//  - staging via pointer bumps (no per-tile 64-bit address mul);
//  - P-pack via v_cvt_pk_bf16_f32 (T12) instead of manual f2bf.
// LDS layout (one array, byte offsets): P@0 (8KB, 2KB/wave), K0@8192,
// K1@24576, V0@40960, V1@57344 — total 73728 B (same 72KB as R3).
__global__ __launch_bounds__(256) void attn_fwd(
    const unsigned short* __restrict__ qkv,
    const unsigned short* __restrict__ vt,
    unsigned short* __restrict__ ctx) {
  __shared__ char lds[73728];
  const int tid = threadIdx.x;
  const int wave = tid >> 6;
  const int lane = tid & 63;
  const int l15 = lane & 15, l16 = lane >> 4;
  const int h = blockIdx.y;
  const int q0 = blockIdx.x * 64 + wave * 16;
  const float SCL = 0.08838834764831845f * 1.4426950408889634f;  // 1/sqrt(128)*log2(e)

  short8 qf[4];
#pragma unroll
  for (int kk = 0; kk < 4; ++kk)
    qf[kk] = *(const short8*)(qkv + (size_t)(q0 + l15) * QKV_LD + h * HD + kk * 32 + l16 * 8);

  f32x4 acc_o[8] = {};
  float m_r = -1e30f;
  float l_r = 0.f;

  // ---- loop-invariant per-lane LDS base pointers (offset-immediate reads) ----
  const int xm = (l15 & 7) << 4;
  // K reads: addr = K0 + BUF + c*4096 + l15*256 + ((kk*64 + l16*16) ^ xm)
  const char* krd0 = lds + 8192 + l15 * 256 + ((l16 * 16) ^ xm);
  const char* krd1 = lds + 8192 + l15 * 256 + ((64 + l16 * 16) ^ xm);
  // V reads: addr = V0 + BUF + d*2048 + l15*128 + ((kk*64 + l16*16) ^ xm)
  const char* vrd0 = lds + 40960 + l15 * 128 + ((l16 * 16) ^ xm);
  const char* vrd1 = lds + 40960 + l15 * 128 + ((64 + l16 * 16) ^ xm);
  // P write: addr = wave*2048 + ((l15*128 + c*32 + l16*8) ^ xm)  [c compile-time]
  char* pwr0 = lds + wave * 2048 + ((l15 * 128 + 0 * 32 + l16 * 8) ^ xm);
  char* pwr1 = lds + wave * 2048 + ((l15 * 128 + 1 * 32 + l16 * 8) ^ xm);
  char* pwr2 = lds + wave * 2048 + ((l15 * 128 + 2 * 32 + l16 * 8) ^ xm);
  char* pwr3 = lds + wave * 2048 + ((l15 * 128 + 3 * 32 + l16 * 8) ^ xm);
  // P read: addr = wave*2048 + l15*128 + ((kk*64 + l16*16) ^ xm)
  const char* prd0 = lds + wave * 2048 + l15 * 128 + ((l16 * 16) ^ xm);
  const char* prd1 = lds + wave * 2048 + l15 * 128 + ((64 + l16 * 16) ^ xm);
  // staging LDS destinations (wave-uniform base; lane x16B applied by HW)
  char* kdst = lds + 8192 + wave * 1024;
  char* vdst = lds + 40960 + wave * 1024;

  // staging global source pointers (inverse-swizzled), bumped per tile
  const unsigned short* kp[4];
  const unsigned short* vp[4];
#pragma unroll
  for (int i = 0; i < 4; ++i) {
    int lin = i * 4096 + tid * 16;
    int r = lin >> 8;                       // K tile: 256B rows
    int cb = lin & 255;
    kp[i] = qkv + 2048 + h * HD + (size_t)r * QKV_LD + ((cb ^ ((r & 7) << 4)) >> 1);
    r = lin >> 7;                           // V tile: 128B rows
    cb = lin & 127;
    vp[i] = vt + (size_t)h * HD * T_LEN + (size_t)r * T_LEN + ((cb ^ ((r & 7) << 4)) >> 1);
  }

#define STAGE_KV(BUFOFF)                                                               \
  do {                                                                                 \
    _Pragma("unroll")                                                                  \
    for (int i = 0; i < 4; ++i) {                                                      \
      GLDS16(kp[i], kdst + (BUFOFF) + i * 4096);                                       \
      GLDS16(vp[i], vdst + (BUFOFF) + i * 4096);                                       \
      kp[i] += 64 * QKV_LD;                                                            \
      vp[i] += 64;                                                                     \
    }                                                                                  \
  } while (0)

#define COMPUTE(BUFOFF)                                                                \
  do {                                                                                 \
    /* S^T = K Q^T : lane (l15,l16) holds S[kv=c*16+l16*4+j][q=l15] */                 \
    f32x4 st[4] = {};                                                                  \
    _Pragma("unroll")                                                                  \
    for (int c = 0; c < 4; ++c) {                                                      \
      st[c] = mfma16(*(const short8*)(krd0 + (BUFOFF) + c * 4096), qf[0], st[c]);      \
      st[c] = mfma16(*(const short8*)(krd1 + (BUFOFF) + c * 4096), qf[1], st[c]);      \
      st[c] = mfma16(*(const short8*)(krd0 + (BUFOFF) + 128 + c * 4096), qf[2], st[c]);\
      st[c] = mfma16(*(const short8*)(krd1 + (BUFOFF) + 128 + c * 4096), qf[3], st[c]);\
    }                                                                                  \
    /* online softmax, lane-local for q-row l15 */                                     \
    float ma = max3f(st[0][0], st[0][1], st[0][2]);                                    \
    float mb = max3f(st[0][3], st[1][0], st[1][1]);                                    \
    float mc = max3f(st[1][2], st[1][3], st[2][0]);                                    \
    float md = max3f(st[2][1], st[2][2], st[2][3]);                                    \
    float me = max3f(st[3][0], st[3][1], st[3][2]);                                    \
    float pmax = fmaxf(max3f(ma, mb, mc), max3f(md, me, st[3][3])) * SCL;              \
    pmax = fmaxf(pmax, __shfl_xor(pmax, 16));                                          \
    pmax = fmaxf(pmax, __shfl_xor(pmax, 32));                                          \
    if (!__all(pmax - m_r <= 8.0f)) {                                                  \
      float nm = fmaxf(m_r, pmax);                                                     \
      float corr = __builtin_amdgcn_exp2f(m_r - nm);                                   \
      m_r = nm;                                                                        \
      l_r *= corr;                                                                     \
      float cj[4];                                                                     \
      _Pragma("unroll")                                                                \
      for (int j = 0; j < 4; ++j) cj[j] = __shfl(corr, l16 * 4 + j);                   \
      _Pragma("unroll")                                                                \
      for (int d = 0; d < 8; ++d)                                                      \
        _Pragma("unroll")                                                              \
        for (int j = 0; j < 4; ++j) acc_o[d][j] *= cj[j];                              \
    }                                                                                  \
    float p[4][4];                                                                     \
    _Pragma("unroll")                                                                  \
    for (int c = 0; c < 4; ++c)                                                        \
      _Pragma("unroll")                                                                \
      for (int j = 0; j < 4; ++j)                                                      \
        p[c][j] = __builtin_amdgcn_exp2f(st[c][j] * SCL - m_r);                        \
    float s01 = (p[0][0] + p[0][1]) + (p[0][2] + p[0][3]);                             \
    float s23 = (p[1][0] + p[1][1]) + (p[1][2] + p[1][3]);                             \
    float s45 = (p[2][0] + p[2][1]) + (p[2][2] + p[2][3]);                             \
    float s67 = (p[3][0] + p[3][1]) + (p[3][2] + p[3][3]);                             \
    float tsum = (s01 + s23) + (s45 + s67);                                            \
    tsum += __shfl_xor(tsum, 16);                                                      \
    tsum += __shfl_xor(tsum, 32);                                                      \
    l_r += tsum;                                                                       \
    /* P -> LDS via cvt_pk (RNE), 4x ds_write_b64 at precomputed bases */              \
    {                                                                                  \
      uint2v w;                                                                        \
      w.x = cvtpk_bf16(p[0][0], p[0][1]); w.y = cvtpk_bf16(p[0][2], p[0][3]);          \
      *(uint2v*)pwr0 = w;                                                              \
      w.x = cvtpk_bf16(p[1][0], p[1][1]); w.y = cvtpk_bf16(p[1][2], p[1][3]);          \
      *(uint2v*)pwr1 = w;                                                              \
      w.x = cvtpk_bf16(p[2][0], p[2][1]); w.y = cvtpk_bf16(p[2][2], p[2][3]);          \
      *(uint2v*)pwr2 = w;                                                              \
      w.x = cvtpk_bf16(p[3][0], p[3][1]); w.y = cvtpk_bf16(p[3][2], p[3][3]);          \
      *(uint2v*)pwr3 = w;                                                              \
    }                                                                                  \
    /* ctx += P @ V */                                                                 \
    {                                                                                  \
      short8 pa0 = *(const short8*)prd0;                                               \
      short8 pa1 = *(const short8*)prd1;                                               \
      _Pragma("unroll")                                                                \
      for (int d = 0; d < 8; ++d) {                                                    \
        acc_o[d] = mfma16(pa0, *(const short8*)(vrd0 + (BUFOFF) + d * 2048), acc_o[d]);\
        acc_o[d] = mfma16(pa1, *(const short8*)(vrd1 + (BUFOFF) + d * 2048), acc_o[d]);\
      }                                                                                \
    }                                                                                  \
  } while (0)

  // prologue: tile 0 -> buf0
  STAGE_KV(0);
  __syncthreads();

  for (int i = 0; i < 16; ++i) {
    // half A: stage tile 2i+1 -> buf1, compute tile 2i from buf0
    STAGE_KV(16384);
    COMPUTE(0);
    __syncthreads();
    // half B: stage tile 2i+2 -> buf0 (skip on last), compute 2i+1 from buf1
    if (i < 15) STAGE_KV(0);
    COMPUTE(16384);
    __syncthreads();
  }
#undef STAGE_KV
#undef COMPUTE

  float lq[4];
#pragma unroll
  for (int j = 0; j < 4; ++j) lq[j] = 1.0f / __shfl(l_r, l16 * 4 + j);
#pragma unroll
  for (int d = 0; d < 8; ++d)
#pragma unroll
    for (int j = 0; j < 4; ++j) {
      int row = q0 + l16 * 4 + j;
      int col = h * HD + d * 16 + l15;
      ctx[(size_t)row * DIM + col] = f2bf(acc_o[d][j] * lq[j]);
    }
}

// ---------------------------------------------------------------- launcher
extern "C" void kernel_launch(void* const* d_in, const int* in_sizes, int n_in,
                              void* d_out, int out_size, void* d_ws, size_t ws_size,
                              hipStream_t stream) {
  const float* x = (const float*)d_in[0];
  const float* w_in = (const float*)d_in[1];
  const float* w_out = (const float*)d_in[2];

  char* ws = (char*)d_ws;
  unsigned short* xbf  = (unsigned short*)(ws + 0);          //  8 MB
  unsigned short* wibf = (unsigned short*)(ws + 8388608);    // 24 MB
  unsigned short* wobf = (unsigned short*)(ws + 33554432);   //  8 MB
  unsigned short* qkv  = (unsigned short*)(ws + 41943040);   // 24 MB (V third unused)
  unsigned short* ctx  = (unsigned short*)(ws + 67108864);   //  8 MB
  unsigned short* vt   = (unsigned short*)(ws + 75497472);   //  8 MB  (end: 80 MB)

  // fused fp32->bf16 casts (x, w_in, w_out) in one launch
  cast3_f32_bf16<<<2048, 256, 0, stream>>>(
      x, xbf, (T_LEN * DIM) / 4,
      w_in, wibf, (3 * DIM * DIM) / 4,
      w_out, wobf, (DIM * DIM) / 4);

  // qkv = x @ w_in^T; V third written TRANSPOSED directly into vt
  gemm_bt_128<2><<<dim3(48, 16), 256, 0, stream>>>(
      xbf, wibf, (void*)qkv, vt, T_LEN, 3 * DIM, DIM);
  // attention -> ctx [2048 x 2048] bf16
  attn_fwd<<<dim3(32, 16), 256, 0, stream>>>(qkv, vt, ctx);
  // out = ctx @ w_out^T  (fp32) — 128x64 tiles, 512 blocks = 2/CU
  gemm_bt_12864<<<dim3(32, 16), 256, 0, stream>>>(ctx, wobf, (float*)d_out, T_LEN, DIM, DIM);
}

// Round 13
// 168.707 us; speedup vs baseline: 1.5162x; 1.0060x over previous
//
#include <hip/hip_runtime.h>

#define T_LEN 2048
#define DIM 2048
#define NH 16
#define HD 128
#define QKV_LD 6144   // 3*DIM

typedef __attribute__((ext_vector_type(8))) short short8;
typedef __attribute__((ext_vector_type(4))) short short4v;
typedef __attribute__((ext_vector_type(4))) float f32x4;
typedef __attribute__((ext_vector_type(4))) float float4v;
typedef __attribute__((ext_vector_type(4))) unsigned short ushort4v;
typedef __attribute__((ext_vector_type(2))) unsigned int uint2v;

static __device__ __forceinline__ unsigned short f2bf(float f) {
  unsigned u = __builtin_bit_cast(unsigned, f);
  u += 0x7fffu + ((u >> 16) & 1u);   // round-to-nearest-even
  return (unsigned short)(u >> 16);
}

static __device__ __forceinline__ unsigned cvtpk_bf16(float lo, float hi) {
  unsigned r;
  asm("v_cvt_pk_bf16_f32 %0, %1, %2" : "=v"(r) : "v"(lo), "v"(hi));
  return r;   // lo in bits [15:0], hi in [31:16], RNE
}

static __device__ __forceinline__ float max3f(float a, float b, float c) {
  return fmaxf(fmaxf(a, b), c);      // clang fuses to v_max3_f32
}

static __device__ __forceinline__ f32x4 mfma16(short8 a, short8 b, f32x4 c) {
  return __builtin_amdgcn_mfma_f32_16x16x32_bf16(a, b, c, 0, 0, 0);
}

#define GLDS16(SRC, DST)                                                            \
  __builtin_amdgcn_global_load_lds((__attribute__((address_space(1))) void*)(SRC),  \
                                   (__attribute__((address_space(3))) void*)(DST),  \
                                   16, 0, 0)

// ---------------------------------------------------------------- fused casts
__global__ void cast3_f32_bf16(const float* __restrict__ a, unsigned short* __restrict__ oa, int na4,
                               const float* __restrict__ b, unsigned short* __restrict__ ob, int nb4,
                               const float* __restrict__ c, unsigned short* __restrict__ oc, int nc4) {
  const int stride = gridDim.x * blockDim.x;
  const int g = blockIdx.x * blockDim.x + threadIdx.x;
#define CAST_LOOP(SRC, DST, N4)                                  \
  for (int i = g; i < (N4); i += stride) {                       \
    float4v f = ((const float4v*)(SRC))[i];                      \
    ushort4v o;                                                  \
    o.x = f2bf(f.x); o.y = f2bf(f.y);                            \
    o.z = f2bf(f.z); o.w = f2bf(f.w);                            \
    ((ushort4v*)(DST))[i] = o;                                   \
  }
  CAST_LOOP(a, oa, na4)
  CAST_LOOP(b, ob, nb4)
  CAST_LOOP(c, oc, nc4)
#undef CAST_LOOP
}

// ---------------------------------------------------------------- GEMM 128x128 (m97)
// MODE 2: qkv fused — Q/K thirds bf16 row-major into Cv; V third transposed
// bf16 into vt[h][d][s].
template <int MODE>
__global__ __launch_bounds__(256) void gemm_bt_128(
    const unsigned short* __restrict__ A,
    const unsigned short* __restrict__ B,
    void* __restrict__ Cv, unsigned short* __restrict__ vt,
    int M, int N, int K) {
  __shared__ unsigned short As[128 * 64];
  __shared__ unsigned short Bs[128 * 64];
  const int tid = threadIdx.x;
  const int wave = tid >> 6;
  const int lane = tid & 63;
  const int l15 = lane & 15, l16 = lane >> 4;
  const int bm = blockIdx.y * 128;
  const int bn = blockIdx.x * 128;
  const int wr = wave >> 1, wc = wave & 1;

  f32x4 acc[4][4] = {};

  int srow[4], scol[4];
#pragma unroll
  for (int i = 0; i < 4; ++i) {
    int lin = i * 4096 + tid * 16;
    int row = lin >> 7;
    int cb = lin & 127;
    srow[i] = row;
    scol[i] = (cb ^ ((row & 7) << 4)) >> 1;
  }

  for (int k0 = 0; k0 < K; k0 += 64) {
#pragma unroll
    for (int i = 0; i < 4; ++i) {
      GLDS16(A + (size_t)(bm + srow[i]) * K + k0 + scol[i], As + i * 2048 + wave * 512);
      GLDS16(B + (size_t)(bn + srow[i]) * K + k0 + scol[i], Bs + i * 2048 + wave * 512);
    }
    __syncthreads();
#pragma unroll
    for (int kk = 0; kk < 2; ++kk) {
      const int cb = kk * 64 + l16 * 16;
      short8 af[4], bfr[4];
#pragma unroll
      for (int m = 0; m < 4; ++m) {
        int row = wr * 64 + m * 16 + l15;
        af[m] = *(const short8*)((const char*)As + row * 128 + (cb ^ ((row & 7) << 4)));
      }
#pragma unroll
      for (int n = 0; n < 4; ++n) {
        int row = wc * 64 + n * 16 + l15;
        bfr[n] = *(const short8*)((const char*)Bs + row * 128 + (cb ^ ((row & 7) << 4)));
      }
#pragma unroll
      for (int m = 0; m < 4; ++m)
#pragma unroll
        for (int n = 0; n < 4; ++n)
          acc[m][n] = mfma16(af[m], bfr[n], acc[m][n]);
    }
    __syncthreads();
  }

  const bool vthird = (MODE == 2) && (bn >= 2 * DIM);   // wave-uniform
#pragma unroll
  for (int m = 0; m < 4; ++m)
#pragma unroll
    for (int n = 0; n < 4; ++n) {
      int row = bm + wr * 64 + m * 16 + l16 * 4;
      int col = bn + wc * 64 + n * 16 + l15;
      if (MODE == 2 && vthird) {
        short4v w;
#pragma unroll
        for (int j = 0; j < 4; ++j) w[j] = (short)f2bf(acc[m][n][j]);
        *(short4v*)(vt + (size_t)(col - 2 * DIM) * T_LEN + row) = w;
      } else {
#pragma unroll
        for (int j = 0; j < 4; ++j) {
          if (MODE == 0)
            ((float*)Cv)[(size_t)(row + j) * N + col] = acc[m][n][j];
          else
            ((unsigned short*)Cv)[(size_t)(row + j) * N + col] = f2bf(acc[m][n][j]);
        }
      }
    }
}

// ---------------------------------------------------------------- GEMM 128x64 (f32 out)
__global__ __launch_bounds__(256) void gemm_bt_12864(
    const unsigned short* __restrict__ A,
    const unsigned short* __restrict__ B,
    float* __restrict__ C, int M, int N, int K) {
  __shared__ unsigned short As[128 * 64];
  __shared__ unsigned short Bs[64 * 64];
  const int tid = threadIdx.x;
  const int wave = tid >> 6;
  const int lane = tid & 63;
  const int l15 = lane & 15, l16 = lane >> 4;
  const int bm = blockIdx.y * 128;
  const int bn = blockIdx.x * 64;
  const int wr = wave >> 1, wc = wave & 1;

  f32x4 acc[4][2] = {};

  int srow[4], scol[4];
#pragma unroll
  for (int i = 0; i < 4; ++i) {
    int lin = i * 4096 + tid * 16;
    int row = lin >> 7;
    int cb = lin & 127;
    srow[i] = row;
    scol[i] = (cb ^ ((row & 7) << 4)) >> 1;
  }

  for (int k0 = 0; k0 < K; k0 += 64) {
#pragma unroll
    for (int i = 0; i < 4; ++i)
      GLDS16(A + (size_t)(bm + srow[i]) * K + k0 + scol[i], As + i * 2048 + wave * 512);
#pragma unroll
    for (int i = 0; i < 2; ++i)
      GLDS16(B + (size_t)(bn + srow[i]) * K + k0 + scol[i], Bs + i * 2048 + wave * 512);
    __syncthreads();
#pragma unroll
    for (int kk = 0; kk < 2; ++kk) {
      const int cb = kk * 64 + l16 * 16;
      short8 af[4], bfr[2];
#pragma unroll
      for (int m = 0; m < 4; ++m) {
        int row = wr * 64 + m * 16 + l15;
        af[m] = *(const short8*)((const char*)As + row * 128 + (cb ^ ((row & 7) << 4)));
      }
#pragma unroll
      for (int n = 0; n < 2; ++n) {
        int row = wc * 32 + n * 16 + l15;
        bfr[n] = *(const short8*)((const char*)Bs + row * 128 + (cb ^ ((row & 7) << 4)));
      }
#pragma unroll
      for (int m = 0; m < 4; ++m)
#pragma unroll
        for (int n = 0; n < 2; ++n)
          acc[m][n] = mfma16(af[m], bfr[n], acc[m][n]);
    }
    __syncthreads();
  }

#pragma unroll
  for (int m = 0; m < 4; ++m)
#pragma unroll
    for (int n = 0; n < 2; ++n) {
      int row = bm + wr * 64 + m * 16 + l16 * 4;
      int col = bn + wc * 32 + n * 16 + l15;
#pragma unroll
      for (int j = 0; j < 4; ++j)
        C[(size_t)(row + j) * N + col] = acc[m][n][j];
    }
}

// ---------------------------------------------------------------- flash attention
// R12 base (VALU-dieted R3 structure) + T15 two-tile pipeline:
//   iter t: { stage K(t+1), V(t); QK^T(t) -> st_cur; SM+PV(t-1) from st_prev;
//             st_prev = st_cur; barrier }
// QK^T's MFMA cluster co-issues with the previous tile's softmax VALU chain
// (separate pipes, m114) and fills the P LDS-roundtrip latency. Staggered
// staging (K one tile ahead, V in-iter, each read one barrier after its
// stage) keeps the same 2x16KB K + 2x16KB V + 8KB P = 72KB LDS. First pair
// peeled so the hot loop body is branch-free; epilogue runs SM+PV(31).
__global__ __launch_bounds__(256) void attn_fwd(
    const unsigned short* __restrict__ qkv,
    const unsigned short* __restrict__ vt,
    unsigned short* __restrict__ ctx) {
  __shared__ char lds[73728];
  const int tid = threadIdx.x;
  const int wave = tid >> 6;
  const int lane = tid & 63;
  const int l15 = lane & 15, l16 = lane >> 4;
  const int h = blockIdx.y;
  const int q0 = blockIdx.x * 64 + wave * 16;
  const float SCL = 0.08838834764831845f * 1.4426950408889634f;  // 1/sqrt(128)*log2(e)

  short8 qf[4];
#pragma unroll
  for (int kk = 0; kk < 4; ++kk)
    qf[kk] = *(const short8*)(qkv + (size_t)(q0 + l15) * QKV_LD + h * HD + kk * 32 + l16 * 8);

  f32x4 acc_o[8] = {};
  f32x4 stc[4], stp[4];
  float m_r = -1e30f;
  float l_r = 0.f;

  // ---- loop-invariant per-lane LDS base pointers ----
  const int xm = (l15 & 7) << 4;
  // K reads: K0@8192 (+16384 for K1) + c*4096 + l15*256 + ((kk*64+l16*16)^xm)
  const char* krd0 = lds + 8192 + l15 * 256 + ((l16 * 16) ^ xm);
  const char* krd1 = lds + 8192 + l15 * 256 + ((64 + l16 * 16) ^ xm);
  // V reads: V0@40960 (+16384 for V1) + d*2048 + l15*128 + ((kk*64+l16*16)^xm)
  const char* vrd0 = lds + 40960 + l15 * 128 + ((l16 * 16) ^ xm);
  const char* vrd1 = lds + 40960 + l15 * 128 + ((64 + l16 * 16) ^ xm);
  // P write/read (per-wave, @0)
  char* pwr0 = lds + wave * 2048 + ((l15 * 128 + 0 * 32 + l16 * 8) ^ xm);
  char* pwr1 = lds + wave * 2048 + ((l15 * 128 + 1 * 32 + l16 * 8) ^ xm);
  char* pwr2 = lds + wave * 2048 + ((l15 * 128 + 2 * 32 + l16 * 8) ^ xm);
  char* pwr3 = lds + wave * 2048 + ((l15 * 128 + 3 * 32 + l16 * 8) ^ xm);
  const char* prd0 = lds + wave * 2048 + l15 * 128 + ((l16 * 16) ^ xm);
  const char* prd1 = lds + wave * 2048 + l15 * 128 + ((64 + l16 * 16) ^ xm);
  // staging LDS destinations (wave-uniform base)
  char* kdst = lds + 8192 + wave * 1024;
  char* vdst = lds + 40960 + wave * 1024;

  // staging global source pointers (inverse-swizzled), bumped per call
  const unsigned short* kp[4];
  const unsigned short* vp[4];
#pragma unroll
  for (int i = 0; i < 4; ++i) {
    int lin = i * 4096 + tid * 16;
    int r = lin >> 8;                       // K tile: 256B rows
    int cb = lin & 255;
    kp[i] = qkv + 2048 + h * HD + (size_t)r * QKV_LD + ((cb ^ ((r & 7) << 4)) >> 1);
    r = lin >> 7;                           // V tile: 128B rows
    cb = lin & 127;
    vp[i] = vt + (size_t)h * HD * T_LEN + (size_t)r * T_LEN + ((cb ^ ((r & 7) << 4)) >> 1);
  }

#define STAGE_K(BUFOFF)                                                                \
  do {                                                                                 \
    _Pragma("unroll")                                                                  \
    for (int i = 0; i < 4; ++i) {                                                      \
      GLDS16(kp[i], kdst + (BUFOFF) + i * 4096);                                       \
      kp[i] += 64 * QKV_LD;                                                            \
    }                                                                                  \
  } while (0)

#define STAGE_V(BUFOFF)                                                                \
  do {                                                                                 \
    _Pragma("unroll")                                                                  \
    for (int i = 0; i < 4; ++i) {                                                      \
      GLDS16(vp[i], vdst + (BUFOFF) + i * 4096);                                       \
      vp[i] += 64;                                                                     \
    }                                                                                  \
  } while (0)

#define QKT(BUFOFF)                                                                    \
  do {                                                                                 \
    _Pragma("unroll")                                                                  \
    for (int c = 0; c < 4; ++c) {                                                      \
      stc[c] = f32x4{0.f, 0.f, 0.f, 0.f};                                              \
      stc[c] = mfma16(*(const short8*)(krd0 + (BUFOFF) + c * 4096), qf[0], stc[c]);    \
      stc[c] = mfma16(*(const short8*)(krd1 + (BUFOFF) + c * 4096), qf[1], stc[c]);    \
      stc[c] = mfma16(*(const short8*)(krd0 + (BUFOFF) + 128 + c * 4096), qf[2], stc[c]); \
      stc[c] = mfma16(*(const short8*)(krd1 + (BUFOFF) + 128 + c * 4096), qf[3], stc[c]); \
    }                                                                                  \
  } while (0)

#define SMPV(VOFF)                                                                     \
  do {                                                                                 \
    float ma = max3f(stp[0][0], stp[0][1], stp[0][2]);                                 \
    float mb = max3f(stp[0][3], stp[1][0], stp[1][1]);                                 \
    float mc = max3f(stp[1][2], stp[1][3], stp[2][0]);                                 \
    float md = max3f(stp[2][1], stp[2][2], stp[2][3]);                                 \
    float me = max3f(stp[3][0], stp[3][1], stp[3][2]);                                 \
    float pmax = fmaxf(max3f(ma, mb, mc), max3f(md, me, stp[3][3])) * SCL;             \
    pmax = fmaxf(pmax, __shfl_xor(pmax, 16));                                          \
    pmax = fmaxf(pmax, __shfl_xor(pmax, 32));                                          \
    if (!__all(pmax - m_r <= 8.0f)) {                                                  \
      float nm = fmaxf(m_r, pmax);                                                     \
      float corr = __builtin_amdgcn_exp2f(m_r - nm);                                   \
      m_r = nm;                                                                        \
      l_r *= corr;                                                                     \
      float cj[4];                                                                     \
      _Pragma("unroll")                                                                \
      for (int j = 0; j < 4; ++j) cj[j] = __shfl(corr, l16 * 4 + j);                   \
      _Pragma("unroll")                                                                \
      for (int d = 0; d < 8; ++d)                                                      \
        _Pragma("unroll")                                                              \
        for (int j = 0; j < 4; ++j) acc_o[d][j] *= cj[j];                              \
    }                                                                                  \
    float p[4][4];                                                                     \
    _Pragma("unroll")                                                                  \
    for (int c = 0; c < 4; ++c)                                                        \
      _Pragma("unroll")                                                                \
      for (int j = 0; j < 4; ++j)                                                      \
        p[c][j] = __builtin_amdgcn_exp2f(stp[c][j] * SCL - m_r);                       \
    float s01 = (p[0][0] + p[0][1]) + (p[0][2] + p[0][3]);                             \
    float s23 = (p[1][0] + p[1][1]) + (p[1][2] + p[1][3]);                             \
    float s45 = (p[2][0] + p[2][1]) + (p[2][2] + p[2][3]);                             \
    float s67 = (p[3][0] + p[3][1]) + (p[3][2] + p[3][3]);                             \
    float tsum = (s01 + s23) + (s45 + s67);                                            \
    tsum += __shfl_xor(tsum, 16);                                                      \
    tsum += __shfl_xor(tsum, 32);                                                      \
    l_r += tsum;                                                                       \
    {                                                                                  \
      uint2v w;                                                                        \
      w.x = cvtpk_bf16(p[0][0], p[0][1]); w.y = cvtpk_bf16(p[0][2], p[0][3]);          \
      *(uint2v*)pwr0 = w;                                                              \
      w.x = cvtpk_bf16(p[1][0], p[1][1]); w.y = cvtpk_bf16(p[1][2], p[1][3]);          \
      *(uint2v*)pwr1 = w;                                                              \
      w.x = cvtpk_bf16(p[2][0], p[2][1]); w.y = cvtpk_bf16(p[2][2], p[2][3]);          \
      *(uint2v*)pwr2 = w;                                                              \
      w.x = cvtpk_bf16(p[3][0], p[3][1]); w.y = cvtpk_bf16(p[3][2], p[3][3]);          \
      *(uint2v*)pwr3 = w;                                                              \
    }                                                                                  \
    {                                                                                  \
      short8 pa0 = *(const short8*)prd0;                                               \
      short8 pa1 = *(const short8*)prd1;                                               \
      _Pragma("unroll")                                                                \
      for (int d = 0; d < 8; ++d) {                                                    \
        acc_o[d] = mfma16(pa0, *(const short8*)(vrd0 + (VOFF) + d * 2048), acc_o[d]);  \
        acc_o[d] = mfma16(pa1, *(const short8*)(vrd1 + (VOFF) + d * 2048), acc_o[d]);  \
      }                                                                                \
    }                                                                                  \
  } while (0)

#define COPY_ST()                                                                      \
  do {                                                                                 \
    _Pragma("unroll")                                                                  \
    for (int c = 0; c < 4; ++c) stp[c] = stc[c];                                       \
  } while (0)

  // prologue: K(0) -> K[0]
  STAGE_K(0);
  __syncthreads();

  // peeled pair (tiles 0,1): no SM+PV at e=0
  STAGE_K(16384);   // K(1) -> K[1]
  STAGE_V(0);       // V(0) -> V[0]
  QKT(0);           // tile 0 from K[0]
  COPY_ST();
  __syncthreads();

  STAGE_K(0);       // K(2) -> K[0]
  STAGE_V(16384);   // V(1) -> V[1]
  QKT(16384);       // tile 1 from K[1]
  SMPV(0);          // tile 0, V[0]
  COPY_ST();
  __syncthreads();

  // hot loop: pairs (2i, 2i+1), i = 1..15 — branch-free bodies
  for (int i = 1; i < 16; ++i) {
    // even tile 2i: QKT from K[0]; SM+PV(2i-1) from V[1]
    STAGE_K(16384);   // K(2i+1) -> K[1]
    STAGE_V(0);       // V(2i)   -> V[0]
    QKT(0);
    SMPV(16384);
    COPY_ST();
    __syncthreads();
    // odd tile 2i+1: QKT from K[1]; SM+PV(2i) from V[0]
    if (i < 15) STAGE_K(0);   // K(2i+2) -> K[0]
    STAGE_V(16384);           // V(2i+1) -> V[1]
    QKT(16384);
    SMPV(0);
    COPY_ST();
    __syncthreads();
  }

  // epilogue: SM+PV for tile 31 (st in stp, V in V[1])
  SMPV(16384);
#undef STAGE_K
#undef STAGE_V
#undef QKT
#undef SMPV
#undef COPY_ST

  float lq[4];
#pragma unroll
  for (int j = 0; j < 4; ++j) lq[j] = 1.0f / __shfl(l_r, l16 * 4 + j);
#pragma unroll
  for (int d = 0; d < 8; ++d)
#pragma unroll
    for (int j = 0; j < 4; ++j) {
      int row = q0 + l16 * 4 + j;
      int col = h * HD + d * 16 + l15;
      ctx[(size_t)row * DIM + col] = f2bf(acc_o[d][j] * lq[j]);
    }
}

// ---------------------------------------------------------------- launcher
extern "C" void kernel_launch(void* const* d_in, const int* in_sizes, int n_in,
                              void* d_out, int out_size, void* d_ws, size_t ws_size,
                              hipStream_t stream) {
  const float* x = (const float*)d_in[0];
  const float* w_in = (const float*)d_in[1];
  const float* w_out = (const float*)d_in[2];

  char* ws = (char*)d_ws;
  unsigned short* xbf  = (unsigned short*)(ws + 0);          //  8 MB
  unsigned short* wibf = (unsigned short*)(ws + 8388608);    // 24 MB
  unsigned short* wobf = (unsigned short*)(ws + 33554432);   //  8 MB
  unsigned short* qkv  = (unsigned short*)(ws + 41943040);   // 24 MB (V third unused)
  unsigned short* ctx  = (unsigned short*)(ws + 67108864);   //  8 MB
  unsigned short* vt   = (unsigned short*)(ws + 75497472);   //  8 MB  (end: 80 MB)

  // fused fp32->bf16 casts (x, w_in, w_out) in one launch
  cast3_f32_bf16<<<2048, 256, 0, stream>>>(
      x, xbf, (T_LEN * DIM) / 4,
      w_in, wibf, (3 * DIM * DIM) / 4,
      w_out, wobf, (DIM * DIM) / 4);

  // qkv = x @ w_in^T; V third written TRANSPOSED directly into vt
  gemm_bt_128<2><<<dim3(48, 16), 256, 0, stream>>>(
      xbf, wibf, (void*)qkv, vt, T_LEN, 3 * DIM, DIM);
  // attention -> ctx [2048 x 2048] bf16
  attn_fwd<<<dim3(32, 16), 256, 0, stream>>>(qkv, vt, ctx);
  // out = ctx @ w_out^T  (fp32) — 128x64 tiles, 512 blocks = 2/CU
  gemm_bt_12864<<<dim3(32, 16), 256, 0, stream>>>(ctx, wobf, (float*)d_out, T_LEN, DIM, DIM);
}